// Round 5
// baseline (146.984 us; speedup 1.0000x reference)
//
#include <hip/hip_runtime.h>
#include <hip/hip_bf16.h>

#define B_ 256
#define L_ 225
#define D_ 1280
#define H_ 256
#define U_ 256
#define LT 45     // real rows per block-tile (5 * 45 = 225 exact)
#define LTP 48    // padded rows staged/computed

typedef __bf16  bf16x8 __attribute__((ext_vector_type(8)));
typedef float   f32x4  __attribute__((ext_vector_type(4)));
typedef unsigned short u16x8 __attribute__((ext_vector_type(8)));
typedef unsigned short u16x4 __attribute__((ext_vector_type(4)));

__device__ __forceinline__ unsigned short f2bf(float f) {
    union { __hip_bfloat16 h; unsigned short u; } cv;
    cv.h = __float2bfloat16(f);   // RNE
    return cv.u;
}

__device__ __forceinline__ f32x4 bf4_to_f32(u16x4 w) {
    union { unsigned u; float f; } a0, a1, a2, a3;
    a0.u = (unsigned)w[0] << 16; a1.u = (unsigned)w[1] << 16;
    a2.u = (unsigned)w[2] << 16; a3.u = (unsigned)w[3] << 16;
    return (f32x4){a0.f, a1.f, a2.f, a3.f};
}

__device__ __forceinline__ float wredsum(float x) {
#pragma unroll
    for (int off = 32; off > 0; off >>= 1) x += __shfl_xor(x, off, 64);
    return x;
}

// ---------------- kernel 1: W1 [D][U] f32 -> W1t [U][D] bf16 ----------------
__global__ void k_prep_w1t(const float* __restrict__ W1, __hip_bfloat16* __restrict__ w1t) {
    int idx = blockIdx.x * 256 + threadIdx.x;   // idx = k*U_+u
    int k = idx / U_;
    int u = idx % U_;
    w1t[(size_t)u * D_ + k] = __float2bfloat16(W1[idx]);
}

// ------------- kernel 2: ph[b][u] = hidden[b].W2[:,u] + b1[u] + b2[u] -------
__global__ void k_proj_h(const float* __restrict__ hidden, const float* __restrict__ W2,
                         const float* __restrict__ b1, const float* __restrict__ b2,
                         float* __restrict__ ph) {
    __shared__ float sh[H_];
    int b = blockIdx.x;
    int u = threadIdx.x;
    sh[u] = hidden[b * H_ + u];
    __syncthreads();
    float acc = b1[u] + b2[u];
#pragma unroll 8
    for (int h = 0; h < H_; ++h) acc += sh[h] * W2[h * U_ + u];
    ph[b * U_ + u] = acc;
}

// ---------------- kernel 3: L-tiled fused kernel ----------------------------
// 1280 blocks (b = blk/5, tile s = blk%5) x 512 threads. A-tile (48x1280 bf16)
// LDS-resident for GEMM *and* context -> features read from HBM exactly once.
// LDS: A @0 (122880, swizzled) | B @122880 (32768, swizzled) | sV @155648
//      sPh @156672 | sL[8][48] @157696 | sW[48] @159232 | 159424 total
__global__ __launch_bounds__(512) void k_fused(
        const float* __restrict__ feat,
        const __hip_bfloat16* __restrict__ w1t,
        const float* __restrict__ ph,
        const float* __restrict__ Vv,
        float* __restrict__ num,
        float* __restrict__ den) {
    __shared__ __align__(128) char smem[159424];
    char*  sB  = smem + 122880;
    float* sV  = (float*)(smem + 155648);
    float* sPh = (float*)(smem + 156672);
    float* sL  = (float*)(smem + 157696);
    float* sW  = (float*)(smem + 159232);

    const int tid  = threadIdx.x;
    const int lane = tid & 63;
    const int wave = tid >> 6;     // 0..7 = column-wave
    const int blk  = blockIdx.x;
    const int b    = blk / 5;
    const int s5   = blk - b * 5;
    const int l0   = s5 * LT;

    if (tid < 256) { sV[tid] = Vv[tid]; sPh[tid] = ph[b * 256 + tid]; }

    const float* featB = feat + ((size_t)b * L_ + l0) * D_;

    // ---- A-stage: 48 rows x 1280 f32 -> bf16 LDS, swizzled (rows >=45 clamp)
#pragma unroll
    for (int p = 0; p < 15; ++p) {
        int id  = p * 512 + tid;          // 16B-chunk id, 48*160 = 7680 total
        int row = id / 160;
        int c8  = id - row * 160;         // 16B chunk within row (0..159)
        int rc  = row < LT ? row : (LT - 1);
        const float* src = featB + (size_t)rc * D_ + c8 * 8;
        f32x4 v0 = *reinterpret_cast<const f32x4*>(src);
        f32x4 v1 = *reinterpret_cast<const f32x4*>(src + 4);
        u16x8 w;
        w[0] = f2bf(v0[0]); w[1] = f2bf(v0[1]); w[2] = f2bf(v0[2]); w[3] = f2bf(v0[3]);
        w[4] = f2bf(v1[0]); w[5] = f2bf(v1[1]); w[6] = f2bf(v1[2]); w[7] = f2bf(v1[3]);
        *reinterpret_cast<u16x8*>(smem + row * 2560 + ((c8 * 16) ^ ((row & 7) << 4))) = w;
    }

    // B reg-staging: thread handles 4 chunks; linear LDS dest, inverse-swz src
    const __hip_bfloat16* bSrc[4];
    int bDst[4];
#pragma unroll
    for (int pass = 0; pass < 4; ++pass) {
        int sI  = pass * 512 + tid;       // 0..2047
        int u   = sI >> 3;
        int c8s = sI & 7;
        int c8g = c8s ^ (u & 7);
        bSrc[pass] = w1t + (size_t)u * D_ + c8g * 8;
        bDst[pass] = sI * 16;
    }
    u16x8 breg[4];
#pragma unroll
    for (int pass = 0; pass < 4; ++pass)
        breg[pass] = *reinterpret_cast<const u16x8*>(bSrc[pass]);   // kt=0

    f32x4 acc[3][2];
#pragma unroll
    for (int mi = 0; mi < 3; ++mi)
#pragma unroll
        for (int ni = 0; ni < 2; ++ni)
            acc[mi][ni] = (f32x4){0.f, 0.f, 0.f, 0.f};

    const int u0   = wave * 32 + (lane & 15);
    const int bswz0 = (u0 & 7) << 4;
    const int bswz1 = ((u0 + 16) & 7) << 4;
    __syncthreads();   // A visible; B buffer free

    // ---- K-loop: 20 steps of 64, B single-buffered, loads overlap compute --
    for (int kt = 0; kt < 20; ++kt) {
#pragma unroll
        for (int pass = 0; pass < 4; ++pass)
            *reinterpret_cast<u16x8*>(sB + bDst[pass]) = breg[pass];
        if (kt < 19) {
#pragma unroll
            for (int pass = 0; pass < 4; ++pass)
                breg[pass] = *reinterpret_cast<const u16x8*>(bSrc[pass] + (kt + 1) * 64);
        }
        __syncthreads();   // B tile kt visible
#pragma unroll
        for (int ks = 0; ks < 2; ++ks) {
            const int kloc = ks * 64 + ((lane >> 4) << 4);   // byte off in 128B group
            bf16x8 a[3], bb[2];
#pragma unroll
            for (int mi = 0; mi < 3; ++mi) {
                int r = mi * 16 + (lane & 15);
                a[mi] = *reinterpret_cast<const bf16x8*>(
                    smem + r * 2560 + ((kt * 128 + kloc) ^ ((r & 7) << 4)));
            }
            bb[0] = *reinterpret_cast<const bf16x8*>(sB + u0 * 128 + (kloc ^ bswz0));
            bb[1] = *reinterpret_cast<const bf16x8*>(sB + (u0 + 16) * 128 + (kloc ^ bswz1));
#pragma unroll
            for (int mi = 0; mi < 3; ++mi)
#pragma unroll
                for (int ni = 0; ni < 2; ++ni)
                    acc[mi][ni] = __builtin_amdgcn_mfma_f32_16x16x32_bf16(
                        a[mi], bb[ni], acc[mi][ni], 0, 0, 0);
        }
        __syncthreads();   // compute kt done before B overwrite
    }

    // ---- epilogue: tanh(acc+ph)*V -> per-wave partial logits ----
    float ph0 = sPh[u0], ph1 = sPh[u0 + 16];
    float v0  = sV[u0],  v1  = sV[u0 + 16];
#pragma unroll
    for (int mi = 0; mi < 3; ++mi) {
#pragma unroll
        for (int rg = 0; rg < 4; ++rg) {
            int row = mi * 16 + ((lane >> 4) << 2) + rg;   // 0..47
            float x0 = acc[mi][0][rg] + ph0;
            float x1 = acc[mi][1][rg] + ph1;
            float sl = (1.f - 2.f / (__expf(2.f * x0) + 1.f)) * v0
                     + (1.f - 2.f / (__expf(2.f * x1) + 1.f)) * v1;
            sl += __shfl_xor(sl, 1, 64);
            sl += __shfl_xor(sl, 2, 64);
            sl += __shfl_xor(sl, 4, 64);
            sl += __shfl_xor(sl, 8, 64);
            if ((lane & 15) == 0) sL[wave * LTP + row] = sl;
        }
    }
    __syncthreads();

    // ---- weights w = exp(logit) (no max: |logit| <= sum|V| ~ 13) ----
    if (wave == 0) {
        float w = 0.f;
        if (lane < LT) {
            float lg = 0.f;
#pragma unroll
            for (int wc = 0; wc < 8; ++wc) lg += sL[wc * LTP + lane];
            w = __expf(lg);
            sW[lane] = w;
        }
        float d = wredsum(w);
        if (lane == 0) den[blk] = d;
    }
    __syncthreads();

    // ---- context partial from resident LDS A-tile ----
    f32x4 c[5];
#pragma unroll
    for (int ch = 0; ch < 5; ++ch) c[ch] = (f32x4){0.f, 0.f, 0.f, 0.f};
    for (int l = wave; l < LT; l += 8) {
        float wgt = sW[l];
        const char* arow = smem + l * 2560;
        int rswz = (l & 7) << 4;
#pragma unroll
        for (int ch = 0; ch < 5; ++ch) {
            u16x4 w4 = *reinterpret_cast<const u16x4*>(
                arow + ((ch * 512 + lane * 8) ^ rswz));
            c[ch] += wgt * bf4_to_f32(w4);
        }
    }
    __syncthreads();   // all A reads done before overwrite

    // ---- reduce 8 wave partials -> num[blk] ----
    float* pc = (float*)smem;   // [8][1280] f32
#pragma unroll
    for (int ch = 0; ch < 5; ++ch)
        *reinterpret_cast<f32x4*>(pc + wave * 1280 + ch * 256 + (lane << 2)) = c[ch];
    __syncthreads();
    if (tid < 320) {
        f32x4 s = (f32x4){0.f, 0.f, 0.f, 0.f};
#pragma unroll
        for (int w = 0; w < 8; ++w)
            s += *reinterpret_cast<const f32x4*>(pc + w * 1280 + (tid << 2));
        *reinterpret_cast<f32x4*>(num + (size_t)blk * 1280 + (tid << 2)) = s;
    }
}

// ---------------- kernel 4: combine 5 tile-partials per batch ----------------
__global__ void k_combine(const float* __restrict__ num, const float* __restrict__ den,
                          float* __restrict__ out) {
    int b = blockIdx.x;
    int t = threadIdx.x;   // 0..319
    f32x4 n = (f32x4){0.f, 0.f, 0.f, 0.f};
    float d = 0.f;
#pragma unroll
    for (int s = 0; s < 5; ++s) {
        n += *reinterpret_cast<const f32x4*>(num + (size_t)(b * 5 + s) * 1280 + (t << 2));
        d += den[b * 5 + s];
    }
    n *= (1.f / d);
    *reinterpret_cast<f32x4*>(out + (size_t)b * D_ + (t << 2)) = n;
}

extern "C" void kernel_launch(void* const* d_in, const int* in_sizes, int n_in,
                              void* d_out, int out_size, void* d_ws, size_t ws_size,
                              hipStream_t stream) {
    const float* feat   = (const float*)d_in[0];
    const float* hidden = (const float*)d_in[1];
    const float* W1     = (const float*)d_in[2];
    const float* b1     = (const float*)d_in[3];
    const float* W2     = (const float*)d_in[4];
    const float* b2     = (const float*)d_in[5];
    const float* Vv     = (const float*)d_in[6];
    // bV (d_in[7]) is a uniform logit shift -> softmax-invariant; skipped.

    char* ws = (char*)d_ws;
    __hip_bfloat16* w1t = (__hip_bfloat16*)(ws);    // 655360 B
    float* ph  = (float*)(ws + 655360);             // 262144 B
    float* num = (float*)(ws + 917504);             // 1280*1280*4 = 6553600 B
    float* den = (float*)(ws + 7471104);            // 5120 B
    float* out = (float*)d_out;

    k_prep_w1t<<<(U_ * D_) / 256, 256, 0, stream>>>(W1, w1t);
    k_proj_h  <<<B_, U_, 0, stream>>>(hidden, W2, b1, b2, ph);
    k_fused   <<<B_ * 5, 512, 0, stream>>>(feat, w1t, ph, Vv, num, den);
    k_combine <<<B_, 320, 0, stream>>>(num, den, out);
}